// Round 1
// baseline (430.755 us; speedup 1.0000x reference)
//
#include <hip/hip_runtime.h>
#include <cmath>

#define NB 256   // batch = grid
#define NT 512   // seq len
#define ND 50    // emb dim
#define NH 50    // hidden
#define NC 5     // classes
#define NG 200   // 4*NH

__device__ __forceinline__ float rcpf(float x) { return __builtin_amdgcn_rcpf(x); }

__global__ __launch_bounds__(256, 1)
void lstm_fused(const int* __restrict__ x, const int* __restrict__ lengths,
                const float* __restrict__ emb_table,
                const float* __restrict__ W_ih, const float* __restrict__ W_hh,
                const float* __restrict__ b_ih, const float* __restrict__ b_hh,
                const float* __restrict__ W_lin, const float* __restrict__ b_lin,
                float* __restrict__ out)
{
    __shared__ __align__(16) float embbuf[3][52];  // rows t%3, 16B-aligned rows (208B stride)
    __shared__ __align__(16) float hb[2][52];      // h double buffer
    __shared__ float rep[152];

    const int b   = blockIdx.x;
    const int tid = threadIdx.x;
    const int* xrow = x + (size_t)b * NT;

    const bool is_gemv = tid < NG;
    const int  q  = tid & 3;        // gate: 0=i 1=f 2=g 3=o
    const int  k4 = tid >> 2;       // hidden unit
    const bool is_load = (tid >= NG && tid < NG + ND);
    const int  kk = tid - NG;

    // ---------------- prologue ----------------
    float wih[ND], whh[ND];
    float bsum = 0.f, scale = 1.f, addc = 0.f;
    if (is_gemv) {
        const int r = q * NH + k4;                 // row in [4H, D] weights (PyTorch i,f,g,o order)
        #pragma unroll
        for (int j = 0; j < ND; ++j) {
            wih[j] = W_ih[r * ND + j];
            whh[j] = W_hh[r * ND + j];
        }
        bsum = b_ih[r] + b_hh[r];
        if (q == 2) { scale = 2.f; addc = -1.f; }  // tanh(x)=2*sigmoid(2x)-1
    }
    float esum = 0.f, emax = -INFINITY, evR = 0.f;
    if (tid < 52) { hb[0][tid] = 0.f; hb[1][tid] = 0.f; }
    if (is_load) {
        int s0 = xrow[0], s1 = xrow[1], s2 = xrow[2];
        float e0 = emb_table[(size_t)s0 * ND + kk];
        float e1 = emb_table[(size_t)s1 * ND + kk];
        embbuf[0][kk] = e0; embbuf[1][kk] = e1;
        esum = e0 + e1; emax = fmaxf(e0, e1);
        evR  = emb_table[(size_t)s2 * ND + kk];    // row 2, written at t=0
    }
    int sC = xrow[3];                               // idx for row t+3 prefetch (uniform)
    const int lastidx = min(lengths[b], NT) - 1;
    float cst = 0.f, hlast = 0.f;
    __syncthreads();

    // ---------------- sequential scan, ONE barrier per step ----------------
    int bi = 0;   // t % 3
    int ht = 0;   // t & 1
    for (int t = 0; t < NT; ++t) {
        if (is_gemv) {
            const float4* eb  = (const float4*)(&embbuf[bi][0]);
            const float4* hbp = (const float4*)(&hb[ht][0]);
            float a0 = bsum, a1 = 0.f, a2 = 0.f, a3 = 0.f;
            // x-projection (independent of h -> fills h-read latency window)
            #pragma unroll
            for (int j = 0; j < 12; ++j) {
                float4 e = eb[j];
                a0 = fmaf(e.x, wih[4*j+0], a0);
                a1 = fmaf(e.y, wih[4*j+1], a1);
                a2 = fmaf(e.z, wih[4*j+2], a2);
                a3 = fmaf(e.w, wih[4*j+3], a3);
            }
            a0 = fmaf(embbuf[bi][48], wih[48], a0);
            a1 = fmaf(embbuf[bi][49], wih[49], a1);
            // h-projection
            #pragma unroll
            for (int j = 0; j < 12; ++j) {
                float4 h = hbp[j];
                a0 = fmaf(h.x, whh[4*j+0], a0);
                a1 = fmaf(h.y, whh[4*j+1], a1);
                a2 = fmaf(h.z, whh[4*j+2], a2);
                a3 = fmaf(h.w, whh[4*j+3], a3);
            }
            a2 = fmaf(hb[ht][48], whh[48], a2);
            a3 = fmaf(hb[ht][49], whh[49], a3);
            float g = (a0 + a1) + (a2 + a3);
            // unified activation: sigmoid for i,f,o ; tanh for g (scale=2, addc=-1)
            float act = fmaf(rcpf(1.f + __expf(-scale * g)), scale, addc);
            // quad exchange: all 4 gates of unit k4 into every lane of the quad
            float v1 = __shfl_xor(act, 1);
            float v2 = __shfl_xor(act, 2);
            float v3 = __shfl_xor(v1, 2);
            const bool b0 = q & 1, b1 = q & 2;
            float i_  = b1 ? (b0 ? v3 : v2) : (b0 ? v1 : act);
            float f_  = b1 ? (b0 ? v2 : v3) : (b0 ? act : v1);
            float gt_ = b1 ? (b0 ? v1 : act) : (b0 ? v3 : v2);
            float o_  = b1 ? (b0 ? act : v1) : (b0 ? v2 : v3);
            cst = fmaf(f_, cst, i_ * gt_);
            float th = fmaf(rcpf(1.f + __expf(-2.f * cst)), 2.f, -1.f);
            float h = o_ * th;
            if (q == 0) {
                hb[ht ^ 1][k4] = h;
                if (t == lastidx) hlast = h;
            }
        }
        if (is_load) {
            if (t + 2 < NT) {                       // write row t+2 (loaded last step)
                int wi = (bi >= 1) ? bi - 1 : 2;    // (t+2) % 3
                embbuf[wi][kk] = evR;
                esum += evR; emax = fmaxf(emax, evR);
            }
            if (t + 3 < NT)                         // issue load of row t+3
                evR = emb_table[(size_t)sC * ND + kk];
        }
        sC = xrow[(t + 4 < NT) ? t + 4 : NT - 1];   // uniform x prefetch
        __syncthreads();
        bi = (bi == 2) ? 0 : bi + 1;
        ht ^= 1;
    }

    // ---------------- epilogue ----------------
    if (is_gemv && q == 0) rep[k4] = hlast;
    if (is_load) {
        rep[NH + kk]     = esum / (float)lengths[b];
        rep[2 * NH + kk] = emax;
    }
    __syncthreads();
    if (tid < NC) {
        float acc = b_lin[tid];
        for (int j = 0; j < 3 * NH; ++j)
            acc = fmaf(rep[j], W_lin[tid * 3 * NH + j], acc);
        out[(size_t)b * NC + tid] = acc;
    }
}

extern "C" void kernel_launch(void* const* d_in, const int* in_sizes, int n_in,
                              void* d_out, int out_size, void* d_ws, size_t ws_size,
                              hipStream_t stream) {
    const int*   x     = (const int*)d_in[0];
    const int*   len   = (const int*)d_in[1];
    // d_in[2] = bows (unused by the model)
    const float* emb   = (const float*)d_in[3];
    const float* W_ih  = (const float*)d_in[4];
    const float* W_hh  = (const float*)d_in[5];
    const float* b_ih  = (const float*)d_in[6];
    const float* b_hh  = (const float*)d_in[7];
    const float* W_lin = (const float*)d_in[8];
    const float* b_lin = (const float*)d_in[9];
    float* outp = (float*)d_out;

    hipLaunchKernelGGL(lstm_fused, dim3(NB), dim3(256), 0, stream,
                       x, len, emb, W_ih, W_hh, b_ih, b_hh, W_lin, b_lin, outp);
}